// Round 8
// baseline (590.024 us; speedup 1.0000x reference)
//
#include <hip/hip_runtime.h>

// =====================================================================
// CNN encoder, fp32 world via fp16 MFMA (32x32x16 full-rate).
// R8: TWO blocks per CU (M-split halves of each sequence), each with
// its own barrier domain -> true inter-block overlap (R7 proved more
// waves in ONE domain convoy; R5==R6 proved staging structure isn't
// the wall). LDS/block = 79,360 B < 80K. 3-plane ring (dist 2/4).
// Cross-block t-max resolved via ws partials + a tiny tail kernel
// (stream-ordered -> no fences). GEMM1 rows 64..67 via scalar cleanup.
// Fallbacks: R6 kernel (medium ws), dual-world scalar kernel.
// =====================================================================

#define DD   300
#define LL   128
#define TOUT 124
#define BLK  320
// ws layout (bytes): 114 weight planes of 10,240 B; then pmax partials
#define WS_SMALL    1167360
#define WS_PMAX_OFF 1167360
#define WS_BIG      3788800        // + 1024*2*320*4
#define NPH         114

typedef __attribute__((ext_vector_type(8))) _Float16 f16x8;
typedef __attribute__((ext_vector_type(4))) float f32x4;
typedef __attribute__((ext_vector_type(16))) float f32x16;
typedef unsigned int   u32;
typedef unsigned short u16;
typedef __attribute__((ext_vector_type(4))) u32 u32x4;

__device__ __forceinline__ float b2f(u16 u) {
    union { float f; u32 i; } x; x.i = ((u32)u) << 16; return x.f;
}
__device__ __forceinline__ u16 f2bu(float f) {
    union { float f; u32 i; } x; x.f = f;
    u32 r = x.i + 0x7FFFu + ((x.i >> 16) & 1u);
    return (u16)(r >> 16);
}
__device__ __forceinline__ float ld(const void* p, size_t idx, int is32) {
    return is32 ? ((const float*)p)[idx] : b2f(((const u16*)p)[idx]);
}
__device__ __forceinline__ int sniff_is32(const void* W1) {
    int cnt = 0;
    const u32* w1raw = (const u32*)W1;
    for (int i = 0; i < 64; ++i) {
        u32 e = (w1raw[i] >> 7) & 0xFFu;
        cnt += (e >= 100u && e <= 126u) ? 1 : 0;
    }
    return (cnt < 32) ? 1 : 0;
}
__device__ __forceinline__ void barrier_lgkm() {
    asm volatile("s_waitcnt lgkmcnt(0)" ::: "memory");
    __builtin_amdgcn_s_barrier();
}

// ============ transform: weights -> fp16 K-major plane images ============
__global__ void CNNEncoder_36258113912977_xform(
    const void* W1, const void* conv_w, void* ws)
{
    if (!sniff_is32(W1)) return;
    const int kk = blockIdx.x, part = blockIdx.y, tid = threadIdx.x;
    if (part == 0) {
        const float* W1f = (const float*)W1;
        f16x8* dst = (f16x8*)ws + (size_t)kk * 640;
        for (int g = tid; g < 640; g += 512) {
            const int kc = (g >= 320) ? 1 : 0;
            const int nn = g - kc * 320;
            f16x8 v;
            #pragma unroll
            for (int e = 0; e < 8; ++e) {
                const int k = kk * 16 + kc * 8 + e;
                v[e] = (_Float16)((k < DD && nn < DD) ? W1f[(size_t)k * DD + nn] : 0.f);
            }
            dst[g] = v;
        }
    } else {
        const int s = part - 1;
        const float* CWf = (const float*)conv_w;
        f16x8* dst = (f16x8*)((char*)ws + 194560) + (size_t)kk * 3200 + (size_t)s * 640;
        for (int g = tid; g < 640; g += 512) {
            const int kc = (g >= 320) ? 1 : 0;
            const int nn = g - kc * 320;
            f16x8 v;
            #pragma unroll
            for (int e = 0; e < 8; ++e) {
                const int k = kk * 16 + kc * 8 + e;
                v[e] = (_Float16)((k < DD && nn < DD)
                        ? CWf[(size_t)nn * 1500 + (size_t)k * 5 + s] : 0.f);
            }
            dst[g] = v;
        }
    }
}

// ---- scalar cleanup helpers (GEMM1 rows 64..67, half 0 only) ----
__device__ __forceinline__ float clean_dot(const _Float16* XB, const float* W1f,
                                           const float* b1f, int idx) {
    const int rr = (idx >= 900) ? 3 : (idx >= 600) ? 2 : (idx >= 300) ? 1 : 0;
    const int col = idx - 300 * rr;
    const int row = 64 + rr;
    float a = b1f[col];
    for (int kc = 0; kc < 37; ++kc) {
        const f16x8 xv = *(const f16x8*)&XB[row * 320 + ((kc ^ (row & 7)) << 3)];
        #pragma unroll
        for (int e = 0; e < 8; ++e)
            a += (float)xv[e] * W1f[(size_t)(8 * kc + e) * DD + col];
    }
    {
        const f16x8 xv = *(const f16x8*)&XB[row * 320 + ((37 ^ (row & 7)) << 3)];
        #pragma unroll
        for (int e = 0; e < 4; ++e)
            a += (float)xv[e] * W1f[(size_t)(296 + e) * DD + col];
    }
    return a;
}
__device__ __forceinline__ void clean_wr(_Float16* XB, int idx, float v) {
    const int rr = (idx >= 900) ? 3 : (idx >= 600) ? 2 : (idx >= 300) ? 1 : 0;
    const int col = idx - 300 * rr;
    const int row = 64 + rr;
    XB[row * 320 + (((col >> 3) ^ (row & 7)) << 3) + (col & 7)] = (_Float16)v;
}

// ====== main: M-split halves, 2 blocks/CU, 3-plane ring pipeline ======
#define STG2(P, Q, QX) do {                                                 \
    const int wr_ = (P) + 2;                                                \
    if (wr_ < NPH) {                                                        \
        _Float16* d_ = &ring[(wr_ % 3) * 5120];                             \
        *(u32x4*)&d_[tid * 8] = Q;                                          \
        if (tid < 128) *(u32x4*)&d_[(512 + tid) * 8] = QX;                  \
    }                                                                       \
    const int lp_ = (P) + 4;                                                \
    if (lp_ < NPH) {                                                        \
        const u32x4* s_ = (const u32x4*)ws + (size_t)lp_ * 640;             \
        Q = s_[tid];                                                        \
        if (tid < 128) QX = s_[512 + tid];                                  \
    }                                                                       \
} while (0)

#define PH2(P, SROW, KKC, Q, QX) do {                                       \
    STG2((P), Q, QX);                                                       \
    const int c_ = 2 * (KKC) + lh;                                          \
    const int row_ = (wm << 5) + l31 + (SROW);                              \
    const f16x8 a_ = *(const f16x8*)&XB[row_ * 320 + ((c_ ^ (row_ & 7)) << 3)]; \
    const _Float16* bp_ = &ring[((P) % 3) * 5120 + lh * 2560];              \
    __builtin_amdgcn_s_setprio(1);                                          \
    { const f16x8 b_ = *(const f16x8*)&bp_[nn0 * 8];                        \
      acc0 = __builtin_amdgcn_mfma_f32_32x32x16_f16(a_, b_, acc0, 0, 0, 0); } \
    { const f16x8 b_ = *(const f16x8*)&bp_[nn1 * 8];                        \
      acc1 = __builtin_amdgcn_mfma_f32_32x32x16_f16(a_, b_, acc1, 0, 0, 0); } \
    if (nt3) { const f16x8 b_ = *(const f16x8*)&bp_[nn2 * 8];               \
      acc2 = __builtin_amdgcn_mfma_f32_32x32x16_f16(a_, b_, acc2, 0, 0, 0); } \
    __builtin_amdgcn_s_setprio(0);                                          \
    barrier_lgkm();                                                         \
} while (0)

#define PH2_G1(KK, Q, QX)    PH2((KK), 0, (KK), Q, QX)
#define PH2_CV(KK, S, Q, QX) PH2(19 + (KK) * 5 + (S), (S), (KK), Q, QX)

#define EPI2(ACC, TILE) do {                                                \
    const int col_ = (TILE) * 32 + l31;                                     \
    const float bb_ = (col_ < DD) ? b1f[col_] : 0.f;                        \
    const int cc_ = col_ >> 3, c7_ = col_ & 7;                              \
    _Pragma("unroll")                                                       \
    for (int q_ = 0; q_ < 4; ++q_) {                                        \
        _Pragma("unroll")                                                   \
        for (int r_ = 0; r_ < 4; ++r_) {                                    \
            const int row_ = (wm << 5) + q_ * 8 + 4 * lh + r_;              \
            XB[row_ * 320 + ((cc_ ^ (row_ & 7)) << 3) + c7_]                \
                = (_Float16)(ACC[4 * q_ + r_] + bb_);                       \
        } }                                                                 \
} while (0)

#define MAX2(ACC, TILE) do {                                                \
    float m_ = -3.0e38f;                                                    \
    _Pragma("unroll")                                                       \
    for (int q_ = 0; q_ < 4; ++q_) {                                        \
        if (!(half && wm == 1 && q_ == 3)) {                                \
            _Pragma("unroll")                                               \
            for (int r_ = 0; r_ < 4; ++r_) m_ = fmaxf(m_, ACC[4 * q_ + r_]); \
        } else if (lh == 0) {                                               \
            _Pragma("unroll")                                               \
            for (int r_ = 0; r_ < 4; ++r_) m_ = fmaxf(m_, ACC[12 + r_]);    \
        } }                                                                 \
    m_ = fmaxf(m_, __shfl_xor(m_, 32));                                     \
    if (lh == 0) pmax2[wm][(TILE) * 32 + l31] = m_;                         \
} while (0)

__global__ __launch_bounds__(512, 4) void CNNEncoder_36258113912977_kernel(
    const int* __restrict__ tok, const void* mention, const void* emb,
    const void* W1, const void* b1, const void* conv_w, const void* conv_b,
    const void* W2, const void* b2, const void* W3, const void* b3,
    void* out, void* ws)
{
    if (!sniff_is32(W1)) return;

    // 46,080 + 30,720 + 2,560 = 79,360 B  -> 2 blocks/CU
    __shared__ __align__(16) _Float16 XB[72 * 320];    // X, then Xh
    __shared__ __align__(16) _Float16 ring[3 * 5120];  // 3-plane ring
    __shared__ float pmax2[2][320];

    const int bx = blockIdx.x;
    const int n = bx >> 1, half = bx & 1;
    const int tid = threadIdx.x;
    const int w   = tid >> 6;
    const int l   = tid & 63;
    const int l31 = l & 31, lh = l >> 5;
    const int wm  = w >> 2;                   // M tile 0/1 (local rows 32wm..)
    const int wn  = w & 3;                    // N group: tiles {wn, wn+4, wn+8?}
    const bool nt3 = (wn < 2);
    const int nn0 = wn * 32 + l31;
    const int nn1 = nn0 + 128;
    const int nn2 = nn0 + 256;
    const int* trow = tok + (size_t)n * LL;
    const float* b1f = (const float*)b1;
    const float* W1f = (const float*)W1;

    u32x4 qE, qEx, qO, qOx;
    u32x4 p0a, p0b, p1a, p1b;

    // ---- prologue loads: planes 0,1 (direct) + 2,3 (pipeline regs) ----
    {
        const u32x4* wsv = (const u32x4*)ws;
        p0a = wsv[tid];           p1a = wsv[640 + tid];
        qE  = wsv[1280 + tid];    qO  = wsv[1920 + tid];
        if (tid < 128) {
            p0b = wsv[512 + tid];   p1b = wsv[1152 + tid];
            qEx = wsv[1792 + tid];  qOx = wsv[2432 + tid];
        }
    }

    // ---- zero-fill XB (rows 64..71 for half1, pads, zero cols) ----
    for (int i = tid; i < 72 * 160; i += 512) ((u32*)XB)[i] = 0u;
    barrier_lgkm();

    // ---- gather emb rows (half0: global 0..67; half1: global 64..127) ----
    {
        const int nrows = half ? 64 : 68;
        const int r0 = tid >> 3, q0 = tid & 7;
        #pragma unroll
        for (int pass = 0; pass < 2; ++pass) {
            const int r = pass ? (64 + (tid >> 3)) : r0;
            const int q = pass ? (tid & 7) : q0;
            if (pass && (tid >= 32 || r >= nrows)) break;
            const float* erow = (const float*)emb + (size_t)trow[64 * half + r] * DD;
            for (int c = q; c < 38; c += 8) {
                f16x8 v;
                if (c < 37) {
                    const float4 f0 = *(const float4*)(erow + 8 * c);
                    const float4 f1 = *(const float4*)(erow + 8 * c + 4);
                    v[0]=(_Float16)f0.x; v[1]=(_Float16)f0.y;
                    v[2]=(_Float16)f0.z; v[3]=(_Float16)f0.w;
                    v[4]=(_Float16)f1.x; v[5]=(_Float16)f1.y;
                    v[6]=(_Float16)f1.z; v[7]=(_Float16)f1.w;
                } else {
                    const float4 f0 = *(const float4*)(erow + 296);
                    v[0]=(_Float16)f0.x; v[1]=(_Float16)f0.y;
                    v[2]=(_Float16)f0.z; v[3]=(_Float16)f0.w;
                    v[4]=(_Float16)0.f; v[5]=(_Float16)0.f;
                    v[6]=(_Float16)0.f; v[7]=(_Float16)0.f;
                }
                const int p = c ^ (r & 7);
                *(f16x8*)&XB[r * 320 + (p << 3)] = v;
            }
        }
    }

    // ---- write ring planes 0,1 ----
    *(u32x4*)&ring[0 * 5120 + tid * 8] = p0a;
    *(u32x4*)&ring[1 * 5120 + tid * 8] = p1a;
    if (tid < 128) {
        *(u32x4*)&ring[0 * 5120 + (512 + tid) * 8] = p0b;
        *(u32x4*)&ring[1 * 5120 + (512 + tid) * 8] = p1b;
    }
    barrier_lgkm();   // XB + planes 0,1 visible; qE/qO loads in flight

    f32x16 acc0, acc1, acc2;
    #pragma unroll
    for (int j = 0; j < 16; ++j) { acc0[j] = 0.f; acc1[j] = 0.f; acc2[j] = 0.f; }

    // =========== GEMM1: phases 0..18 (rows 0..63) ==========
    for (int kk = 0; kk < 18; kk += 2) {
        PH2_G1(kk,     qE, qEx);
        PH2_G1(kk + 1, qO, qOx);
    }
    PH2_G1(18, qE, qEx);

    // epilogue: +b1, round to fp16, write Xh over XB (own rows/cols)
    EPI2(acc0, wn);
    EPI2(acc1, wn + 4);
    if (nt3) EPI2(acc2, wn + 8);
    __syncthreads();

    // ---- scalar cleanup: Xh rows 64..67 (half0 only; half1 keeps zeros) ----
    if (!half) {
        const int i0 = tid, i1 = tid + 512, i2 = tid + 1024;
        float r0 = clean_dot(XB, W1f, b1f, i0);
        float r1 = clean_dot(XB, W1f, b1f, i1);
        float r2 = (i2 < 1200) ? clean_dot(XB, W1f, b1f, i2) : 0.f;
        __syncthreads();
        clean_wr(XB, i0, r0);
        clean_wr(XB, i1, r1);
        if (i2 < 1200) clean_wr(XB, i2, r2);
    } else {
        __syncthreads();
    }
    barrier_lgkm();

    // ====== conv: phases 19..113 ======
    #pragma unroll
    for (int j = 0; j < 16; ++j) { acc0[j] = 0.f; acc1[j] = 0.f; acc2[j] = 0.f; }

    for (int kk = 0; kk < 18; kk += 2) {
        PH2_CV(kk, 0, qO, qOx);  PH2_CV(kk, 1, qE, qEx);
        PH2_CV(kk, 2, qO, qOx);  PH2_CV(kk, 3, qE, qEx);
        PH2_CV(kk, 4, qO, qOx);
        PH2_CV(kk + 1, 0, qE, qEx);  PH2_CV(kk + 1, 1, qO, qOx);
        PH2_CV(kk + 1, 2, qE, qEx);  PH2_CV(kk + 1, 3, qO, qOx);
        PH2_CV(kk + 1, 4, qE, qEx);
    }
    PH2_CV(18, 0, qO, qOx);  PH2_CV(18, 1, qE, qEx);
    PH2_CV(18, 2, qO, qOx);  PH2_CV(18, 3, qE, qEx);
    PH2_CV(18, 4, qO, qOx);

    // per-wave max over valid t, publish per-M-tile, combine, store to ws
    MAX2(acc0, wn);
    MAX2(acc1, wn + 4);
    if (nt3) MAX2(acc2, wn + 8);
    __syncthreads();

    if (tid < 320) {
        const float m = fmaxf(pmax2[0][tid], pmax2[1][tid]);
        ((float*)((char*)ws + WS_PMAX_OFF))[(size_t)(n * 2 + half) * 320 + tid] = m;
    }
}

// ====== tail: combine halves + MLP (stream-ordered after main) ======
__global__ void CNNEncoder_36258113912977_tail(
    const void* mention, const void* conv_b,
    const void* W2, const void* b2, const void* W3, const void* b3,
    const void* W1, void* out, const void* ws)
{
    if (!sniff_is32(W1)) return;
    __shared__ float cbuf[2 * DD];
    __shared__ float hpart[2][DD];
    __shared__ float hbuf[DD];

    const int n = blockIdx.x, tid = threadIdx.x;
    const float* pm = (const float*)((const char*)ws + WS_PMAX_OFF) + (size_t)n * 640;

    if (tid < DD) {
        const float m = fmaxf(pm[tid], pm[320 + tid]);
        cbuf[tid]      = m + ((const float*)conv_b)[tid];
        cbuf[DD + tid] = ((const float*)mention)[(size_t)n * DD + tid];
    }
    __syncthreads();

    if (tid < 2 * DD) {
        const int part = (tid >= DD) ? 1 : 0;
        const int j = tid - part * DD;
        const float* W2f = (const float*)W2;
        const int c0 = part * DD;
        float a0 = 0.f, a1 = 0.f, a2 = 0.f, a3 = 0.f;
        for (int c = c0; c < c0 + DD; c += 4) {
            a0 += cbuf[c]     * W2f[(size_t)c * DD + j];
            a1 += cbuf[c + 1] * W2f[(size_t)(c + 1) * DD + j];
            a2 += cbuf[c + 2] * W2f[(size_t)(c + 2) * DD + j];
            a3 += cbuf[c + 3] * W2f[(size_t)(c + 3) * DD + j];
        }
        hpart[part][j] = (a0 + a1) + (a2 + a3);
    }
    __syncthreads();
    if (tid < DD)
        hbuf[tid] = tanhf(((const float*)b2)[tid] + hpart[0][tid] + hpart[1][tid]);
    __syncthreads();

    if (tid < 2 * DD) {
        const int part = (tid >= DD) ? 1 : 0;
        const int j = tid - part * DD;
        const float* W3f = (const float*)W3;
        const int c0 = part * 150;
        float a0 = 0.f, a1 = 0.f;
        for (int c = c0; c < c0 + 150; c += 2) {
            a0 += hbuf[c]     * W3f[(size_t)c * DD + j];
            a1 += hbuf[c + 1] * W3f[(size_t)(c + 1) * DD + j];
        }
        hpart[part][j] = a0 + a1;
    }
    __syncthreads();
    if (tid < DD)
        ((float*)out)[(size_t)n * DD + tid]
            = ((const float*)b3)[tid] + hpart[0][tid] + hpart[1][tid];
}

// ====== mid: R6 single-block kernel (medium ws), proven ======
#define STAGE6(P, Q, QX) do {                                               \
    const int wr_ = (P) + 5;                                                \
    if (wr_ < NPH) {                                                        \
        _Float16* d_ = &ring[(wr_ % 6) * 5120];                             \
        *(u32x4*)&d_[tid * 8] = Q;                                          \
        if (tid < 128) *(u32x4*)&d_[(512 + tid) * 8] = QX;                  \
    }                                                                       \
    const int lp_ = (P) + 7;                                                \
    if (lp_ < NPH) {                                                        \
        const u32x4* s_ = (const u32x4*)ws + (size_t)lp_ * 640;             \
        Q = s_[tid];                                                        \
        if (tid < 128) QX = s_[512 + tid];                                  \
    }                                                                       \
} while (0)

#define PH6(P, SROW, KKC, Q, QX) do {                                       \
    STAGE6((P), Q, QX);                                                     \
    const int phys_ = (P) % 6;                                              \
    const int c_ = 2 * (KKC) + lh;                                          \
    const int row_ = mrow0 + l31 + (SROW);                                  \
    const f16x8 a_ = *(const f16x8*)&XB[row_ * 320 + ((c_ ^ (row_ & 7)) << 3)]; \
    __builtin_amdgcn_s_setprio(1);                                          \
    _Pragma("unroll")                                                       \
    for (int nt_ = 0; nt_ < 5; ++nt_) {                                     \
        const int nn_ = nbase + nt_ * 32 + l31;                             \
        const f16x8 b_ = *(const f16x8*)&ring[phys_ * 5120 + lh * 2560 + nn_ * 8]; \
        acc[nt_] = __builtin_amdgcn_mfma_f32_32x32x16_f16(a_, b_, acc[nt_], 0, 0, 0); \
    }                                                                       \
    __builtin_amdgcn_s_setprio(0);                                          \
    barrier_lgkm();                                                         \
} while (0)

#define PH6_G1(KK, Q, QX)    PH6((KK), 0, (KK), Q, QX)
#define PH6_CV(KK, S, Q, QX) PH6(19 + (KK) * 5 + (S), (S), (KK), Q, QX)

__global__ __launch_bounds__(512, 2) void CNNEncoder_36258113912977_mid(
    const int* __restrict__ tok, const void* mention, const void* emb,
    const void* W1, const void* b1, const void* conv_w, const void* conv_b,
    const void* W2, const void* b2, const void* W3, const void* b3,
    void* out, const void* ws)
{
    if (!sniff_is32(W1)) return;

    __shared__ __align__(16) _Float16 XB[132 * 320];
    __shared__ __align__(16) _Float16 ring[6 * 5120];
    __shared__ float pmax4[4][320];
    __shared__ float cbuf[2 * DD];
    __shared__ float hbuf[DD];

    const int n = blockIdx.x, tid = threadIdx.x;
    const int w   = tid >> 6;
    const int l   = tid & 63;
    const int l31 = l & 31, lh = l >> 5;
    const int wm  = w >> 1;
    const int wn  = w & 1;
    const int nbase = wn * 160;
    const int mrow0 = wm * 32;
    const int* trow = tok + (size_t)n * LL;

    u32x4 qE, qO, qEx, qOx;
    u32x4 pre[5], prex[5];

    #pragma unroll
    for (int pl = 0; pl < 5; ++pl) {
        const u32x4* s_ = (const u32x4*)ws + (size_t)pl * 640;
        pre[pl] = s_[tid];
        if (tid < 128) prex[pl] = s_[512 + tid];
    }
    { const u32x4* s_ = (const u32x4*)ws + (size_t)5 * 640;
      qE = s_[tid]; if (tid < 128) qEx = s_[512 + tid]; }
    { const u32x4* s_ = (const u32x4*)ws + (size_t)6 * 640;
      qO = s_[tid]; if (tid < 128) qOx = s_[512 + tid]; }

    for (int i = tid; i < 132 * 160; i += 512) ((u32*)XB)[i] = 0u;
    __syncthreads();

    {
        const int r = tid >> 2, q = tid & 3;
        const float* erow = (const float*)emb + (size_t)trow[r] * DD;
        for (int c = q; c < 38; c += 4) {
            f16x8 v;
            if (c < 37) {
                const float4 f0 = *(const float4*)(erow + 8 * c);
                const float4 f1 = *(const float4*)(erow + 8 * c + 4);
                v[0]=(_Float16)f0.x; v[1]=(_Float16)f0.y;
                v[2]=(_Float16)f0.z; v[3]=(_Float16)f0.w;
                v[4]=(_Float16)f1.x; v[5]=(_Float16)f1.y;
                v[6]=(_Float16)f1.z; v[7]=(_Float16)f1.w;
            } else {
                const float4 f0 = *(const float4*)(erow + 296);
                v[0]=(_Float16)f0.x; v[1]=(_Float16)f0.y;
                v[2]=(_Float16)f0.z; v[3]=(_Float16)f0.w;
                v[4]=(_Float16)0.f; v[5]=(_Float16)0.f;
                v[6]=(_Float16)0.f; v[7]=(_Float16)0.f;
            }
            const int p = c ^ (r & 7);
            *(f16x8*)&XB[r * 320 + (p << 3)] = v;
        }
    }

    #pragma unroll
    for (int pl = 0; pl < 5; ++pl) {
        *(u32x4*)&ring[pl * 5120 + tid * 8] = pre[pl];
        if (tid < 128) *(u32x4*)&ring[pl * 5120 + (512 + tid) * 8] = prex[pl];
    }
    __syncthreads();

    f32x16 acc[5];
    #pragma unroll
    for (int nt = 0; nt < 5; ++nt)
        #pragma unroll
        for (int j = 0; j < 16; ++j) acc[nt][j] = 0.f;

    for (int kk = 0; kk < 18; kk += 2) {
        PH6_G1(kk,     qE, qEx);
        PH6_G1(kk + 1, qO, qOx);
    }
    PH6_G1(18, qE, qEx);

    {
        const float* b1f = (const float*)b1;
        #pragma unroll
        for (int nt = 0; nt < 5; ++nt) {
            const int col = nbase + nt * 32 + l31;
            const float bb = (col < DD) ? b1f[col] : 0.f;
            const int cc = col >> 3, c7 = col & 7;
            #pragma unroll
            for (int q = 0; q < 4; ++q) {
                #pragma unroll
                for (int r = 0; r < 4; ++r) {
                    const int row = mrow0 + q * 8 + 4 * lh + r;
                    XB[row * 320 + ((cc ^ (row & 7)) << 3) + c7]
                        = (_Float16)(acc[nt][4 * q + r] + bb);
                }
            }
        }
    }
    __syncthreads();

    #pragma unroll
    for (int nt = 0; nt < 5; ++nt)
        #pragma unroll
        for (int j = 0; j < 16; ++j) acc[nt][j] = 0.f;

    for (int kk = 0; kk < 18; kk += 2) {
        PH6_CV(kk, 0, qO, qOx);  PH6_CV(kk, 1, qE, qEx);
        PH6_CV(kk, 2, qO, qOx);  PH6_CV(kk, 3, qE, qEx);
        PH6_CV(kk, 4, qO, qOx);
        PH6_CV(kk + 1, 0, qE, qEx);  PH6_CV(kk + 1, 1, qO, qOx);
        PH6_CV(kk + 1, 2, qE, qEx);  PH6_CV(kk + 1, 3, qO, qOx);
        PH6_CV(kk + 1, 4, qE, qEx);
    }
    PH6_CV(18, 0, qO, qOx);  PH6_CV(18, 1, qE, qEx);
    PH6_CV(18, 2, qO, qOx);  PH6_CV(18, 3, qE, qEx);
    PH6_CV(18, 4, qO, qOx);

    #pragma unroll
    for (int nt = 0; nt < 5; ++nt) {
        float m = -3.0e38f;
        #pragma unroll
        for (int q = 0; q < 4; ++q) {
            if (!(wm == 3 && q == 3)) {
                #pragma unroll
                for (int r = 0; r < 4; ++r) m = fmaxf(m, acc[nt][4 * q + r]);
            } else if (lh == 0) {
                #pragma unroll
                for (int r = 0; r < 4; ++r) m = fmaxf(m, acc[nt][12 + r]);
            }
        }
        m = fmaxf(m, __shfl_xor(m, 32));
        if (lh == 0) pmax4[wm][nbase + nt * 32 + l31] = m;
    }
    __syncthreads();

    if (tid < DD) {
        float m = fmaxf(fmaxf(pmax4[0][tid], pmax4[1][tid]),
                        fmaxf(pmax4[2][tid], pmax4[3][tid]));
        cbuf[tid]      = m + ((const float*)conv_b)[tid];
        cbuf[DD + tid] = ((const float*)mention)[(size_t)n * DD + tid];
    }
    __syncthreads();

    if (tid < DD) {
        const float* W2f = (const float*)W2;
        float a0 = 0.f, a1 = 0.f, a2 = 0.f, a3 = 0.f;
        for (int c = 0; c < 2 * DD; c += 4) {
            a0 += cbuf[c]     * W2f[(size_t)c * DD + tid];
            a1 += cbuf[c + 1] * W2f[(size_t)(c + 1) * DD + tid];
            a2 += cbuf[c + 2] * W2f[(size_t)(c + 2) * DD + tid];
            a3 += cbuf[c + 3] * W2f[(size_t)(c + 3) * DD + tid];
        }
        hbuf[tid] = tanhf(((const float*)b2)[tid] + (a0 + a1) + (a2 + a3));
    }
    __syncthreads();

    if (tid < DD) {
        const float* W3f = (const float*)W3;
        float a0 = 0.f, a1 = 0.f;
        for (int c = 0; c < DD; c += 2) {
            a0 += hbuf[c]     * W3f[(size_t)c * DD + tid];
            a1 += hbuf[c + 1] * W3f[(size_t)(c + 1) * DD + tid];
        }
        ((float*)out)[(size_t)n * DD + tid] = ((const float*)b3)[tid] + a0 + a1;
    }
}

// ======== fallback: dual-world scalar kernel ========
// Runs for bf16 world always; for fp32 world only when force32 (tiny ws).
#define CH   16
#define XR   20
#define NSTG 8
__global__ void CNNEncoder_36258113912977_fallback(
    const int* tok, const void* mention, const void* emb,
    const void* W1, const void* b1, const void* conv_w, const void* conv_b,
    const void* W2, const void* b2, const void* W3, const void* b3,
    void* out, int force32)
{
    __shared__ float g[XR * DD];
    __shared__ float xh[XR * DD];
    __shared__ float concat[2 * DD];
    __shared__ float hbuf[DD];

    const int n = blockIdx.x, tid = threadIdx.x;
    const int* trow = tok + (size_t)n * LL;

    const int is32 = sniff_is32(W1);
    if (is32 && !force32) return;

    float mmax = -3.0e38f;

    for (int stage = 0; stage < NSTG; ++stage) {
        const int tbase = stage * CH;
        __syncthreads();

        for (int i = tid; i < XR * DD; i += BLK) {
            int r = i / DD, c = i - (i / DD) * DD;
            int gr = tbase + r; if (gr > 127) gr = 127;
            g[i] = ld(emb, (size_t)trow[gr] * DD + c, is32);
        }
        __syncthreads();

        if (tid < DD) {
            float acc[XR];
            #pragma unroll
            for (int r = 0; r < XR; ++r) acc[r] = 0.f;
            for (int k = 0; k < DD; ++k) {
                float wv = ld(W1, (size_t)k * DD + tid, is32);
                #pragma unroll
                for (int r = 0; r < XR; ++r) acc[r] += g[r * DD + k] * wv;
            }
            float bb = ld(b1, tid, is32);
            #pragma unroll
            for (int r = 0; r < XR; ++r) xh[r * DD + tid] = acc[r] + bb;
        }
        __syncthreads();

        if (tid < DD) {
            float y[CH];
            #pragma unroll
            for (int t = 0; t < CH; ++t) y[t] = 0.f;
            const size_t cwoff = (size_t)tid * (DD * 5);
            for (int k = 0; k < DD; ++k) {
                #pragma unroll
                for (int s = 0; s < 5; ++s) {
                    float wv = ld(conv_w, cwoff + k * 5 + s, is32);
                    #pragma unroll
                    for (int t = 0; t < CH; ++t)
                        y[t] += xh[(t + s) * DD + k] * wv;
                }
            }
            #pragma unroll
            for (int t = 0; t < CH; ++t) {
                int tt = tbase + t;
                if (tt < TOUT) mmax = fmaxf(mmax, y[t]);
            }
        }
    }

    __syncthreads();
    if (tid < DD) {
        concat[tid]      = mmax + ld(conv_b, tid, is32);
        concat[DD + tid] = ld(mention, (size_t)n * DD + tid, is32);
    }
    __syncthreads();

    if (tid < DD) {
        float a = ld(b2, tid, is32);
        for (int c = 0; c < 2 * DD; ++c)
            a += concat[c] * ld(W2, (size_t)c * DD + tid, is32);
        hbuf[tid] = tanhf(a);
    }
    __syncthreads();

    if (tid < DD) {
        float a = ld(b3, tid, is32);
        for (int c = 0; c < DD; ++c)
            a += hbuf[c] * ld(W3, (size_t)c * DD + tid, is32);
        size_t o = (size_t)n * DD + tid;
        if (is32) ((float*)out)[o] = a;
        else      ((u16*)out)[o] = f2bu(a);
    }
}

extern "C" void kernel_launch(void* const* d_in, const int* in_sizes, int n_in,
                              void* d_out, int out_size, void* d_ws, size_t ws_size,
                              hipStream_t stream)
{
    const int small_ok = (d_ws != nullptr) && ws_size >= (size_t)WS_SMALL;
    const int big_ok   = (d_ws != nullptr) && ws_size >= (size_t)WS_BIG;

    if (small_ok)
        CNNEncoder_36258113912977_xform<<<dim3(19, 6), 512, 0, stream>>>(
            d_in[3], d_in[5], d_ws);

    if (big_ok) {
        CNNEncoder_36258113912977_kernel<<<2048, 512, 0, stream>>>(
            (const int*)d_in[0], d_in[1], d_in[2], d_in[3], d_in[4], d_in[5],
            d_in[6], d_in[7], d_in[8], d_in[9], d_in[10], d_out, d_ws);
        CNNEncoder_36258113912977_tail<<<1024, 640, 0, stream>>>(
            d_in[1], d_in[6], d_in[7], d_in[8], d_in[9], d_in[10],
            d_in[3], d_out, d_ws);
    } else if (small_ok) {
        CNNEncoder_36258113912977_mid<<<1024, 512, 0, stream>>>(
            (const int*)d_in[0], d_in[1], d_in[2], d_in[3], d_in[4], d_in[5],
            d_in[6], d_in[7], d_in[8], d_in[9], d_in[10], d_out, d_ws);
    }

    CNNEncoder_36258113912977_fallback<<<1024, BLK, 0, stream>>>(
        (const int*)d_in[0], d_in[1], d_in[2], d_in[3], d_in[4], d_in[5],
        d_in[6], d_in[7], d_in[8], d_in[9], d_in[10], d_out,
        small_ok ? 0 : 1);
}

// Round 9
// 487.164 us; speedup vs baseline: 1.2111x; 1.2111x over previous
//
#include <hip/hip_runtime.h>

// =====================================================================
// CNN encoder, fp32 world via fp16 MFMA (32x32x16 full-rate).
// R9: BARRIER-FREE K-loop. R5..R8 proved the wall is the barrier-
// synchronized shared-LDS B-slab (every structure ~320+ us). Fix:
// stream B fragments directly from the L2-resident ws image
// (coalesced 16B/lane, 512B/half-wave), software-pipelined one phase
// ahead in parity registers. LDS holds only XB (A operand). Waves
// run free through all 114 phases; 3 barriers total in the kernel.
// Wave grid 2M x 4N, mt=2 per wave -> each B load feeds 2 MFMAs
// (L2 traffic 2.3 GB/launch ~ 67 us; MFMA floor ~65 us).
// Fallback: dual-world scalar kernel (tiny-ws / bf16 worlds).
// =====================================================================

#define DD   300
#define LL   128
#define TOUT 124
#define BLK  320
#define WS_SMALL 1167360          // 114 planes x 10,240 B

typedef __attribute__((ext_vector_type(8))) _Float16 f16x8;
typedef __attribute__((ext_vector_type(16))) float f32x16;
typedef unsigned int   u32;
typedef unsigned short u16;

__device__ __forceinline__ float b2f(u16 u) {
    union { float f; u32 i; } x; x.i = ((u32)u) << 16; return x.f;
}
__device__ __forceinline__ u16 f2bu(float f) {
    union { float f; u32 i; } x; x.f = f;
    u32 r = x.i + 0x7FFFu + ((x.i >> 16) & 1u);
    return (u16)(r >> 16);
}
__device__ __forceinline__ float ld(const void* p, size_t idx, int is32) {
    return is32 ? ((const float*)p)[idx] : b2f(((const u16*)p)[idx]);
}
__device__ __forceinline__ int sniff_is32(const void* W1) {
    int cnt = 0;
    const u32* w1raw = (const u32*)W1;
    for (int i = 0; i < 64; ++i) {
        u32 e = (w1raw[i] >> 7) & 0xFFu;
        cnt += (e >= 100u && e <= 126u) ? 1 : 0;
    }
    return (cnt < 32) ? 1 : 0;
}

// ============ transform: weights -> fp16 K-major plane images ============
// plane p (10,240 B) = [kc(2)][nn(320)][8 fp16]; p 0..18 = W1 K-steps,
// p 19..113 = conv (kk,s) planes in phase order (5 s per kk).
__global__ void CNNEncoder_36258113912977_xform(
    const void* W1, const void* conv_w, void* ws)
{
    if (!sniff_is32(W1)) return;
    const int kk = blockIdx.x, part = blockIdx.y, tid = threadIdx.x;
    if (part == 0) {
        const float* W1f = (const float*)W1;
        f16x8* dst = (f16x8*)ws + (size_t)kk * 640;
        for (int g = tid; g < 640; g += 512) {
            const int kc = (g >= 320) ? 1 : 0;
            const int nn = g - kc * 320;
            f16x8 v;
            #pragma unroll
            for (int e = 0; e < 8; ++e) {
                const int k = kk * 16 + kc * 8 + e;
                v[e] = (_Float16)((k < DD && nn < DD) ? W1f[(size_t)k * DD + nn] : 0.f);
            }
            dst[g] = v;
        }
    } else {
        const int s = part - 1;
        const float* CWf = (const float*)conv_w;
        // abs plane = 19 + kk*5 + s
        f16x8* dst = (f16x8*)ws + (size_t)(19 + kk * 5 + s) * 640;
        for (int g = tid; g < 640; g += 512) {
            const int kc = (g >= 320) ? 1 : 0;
            const int nn = g - kc * 320;
            f16x8 v;
            #pragma unroll
            for (int e = 0; e < 8; ++e) {
                const int k = kk * 16 + kc * 8 + e;
                v[e] = (_Float16)((k < DD && nn < DD)
                        ? CWf[(size_t)nn * 1500 + (size_t)k * 5 + s] : 0.f);
            }
            dst[g] = v;
        }
    }
}

#define MM(A, B, C) __builtin_amdgcn_mfma_f32_32x32x16_f16((A), (B), (C), 0, 0, 0)

// GEMM1 phase CP (0..18): consume current-parity regs, prefetch next.
// At CP==18 prefetch conv plane 19's B instead.
#define G1(CP, BC0, BC1, BC2, AC0, AC1, BN0, BN1, BN2, AN0, AN1) do {        \
    if ((CP) + 1 < 19) {                                                     \
        const f16x8* wp_ = wsp + (size_t)((CP) + 1) * 640;                   \
        BN0 = wp_[bg0]; BN1 = wp_[bg1]; if (nt3) BN2 = wp_[bg2];             \
        const int c_ = 2 * ((CP) + 1) + lh;                                  \
        { const int r_ = mrow0 + l31;                                        \
          AN0 = *(const f16x8*)&XB[r_ * 320 + ((c_ ^ (r_ & 7)) << 3)]; }     \
        { const int r_ = mrow0 + 32 + l31;                                   \
          AN1 = *(const f16x8*)&XB[r_ * 320 + ((c_ ^ (r_ & 7)) << 3)]; }     \
    } else {                                                                 \
        const f16x8* wp_ = wsp + (size_t)19 * 640;                           \
        BN0 = wp_[bg0]; BN1 = wp_[bg1]; if (nt3) BN2 = wp_[bg2];             \
    }                                                                        \
    __builtin_amdgcn_s_setprio(1);                                           \
    acc00 = MM(AC0, BC0, acc00);  acc10 = MM(AC1, BC0, acc10);               \
    acc01 = MM(AC0, BC1, acc01);  acc11 = MM(AC1, BC1, acc11);               \
    if (nt3) { acc02 = MM(AC0, BC2, acc02);  acc12 = MM(AC1, BC2, acc12); }  \
    __builtin_amdgcn_s_setprio(0);                                           \
} while (0)

// conv relative phase CP (0..94), abs plane 19+CP, s = CP%5, kk = CP/5.
#define CV(CP, BC0, BC1, BC2, AC0, AC1, BN0, BN1, BN2, AN0, AN1) do {        \
    if ((CP) + 1 < 95) {                                                     \
        const f16x8* wp_ = wsp + (size_t)(20 + (CP)) * 640;                  \
        BN0 = wp_[bg0]; BN1 = wp_[bg1]; if (nt3) BN2 = wp_[bg2];             \
        const int nk_ = ((CP) + 1) / 5, ns_ = ((CP) + 1) % 5;                \
        const int c_ = 2 * nk_ + lh;                                         \
        { const int r_ = mrow0 + l31 + ns_;                                  \
          AN0 = *(const f16x8*)&XB[r_ * 320 + ((c_ ^ (r_ & 7)) << 3)]; }     \
        { const int r_ = mrow0 + 32 + l31 + ns_;                             \
          AN1 = *(const f16x8*)&XB[r_ * 320 + ((c_ ^ (r_ & 7)) << 3)]; }     \
    }                                                                        \
    __builtin_amdgcn_s_setprio(1);                                           \
    acc00 = MM(AC0, BC0, acc00);  acc10 = MM(AC1, BC0, acc10);               \
    acc01 = MM(AC0, BC1, acc01);  acc11 = MM(AC1, BC1, acc11);               \
    if (nt3) { acc02 = MM(AC0, BC2, acc02);  acc12 = MM(AC1, BC2, acc12); }  \
    __builtin_amdgcn_s_setprio(0);                                           \
} while (0)

#define EPI(ACC, MT, TILE) do {                                              \
    const int col_ = (TILE) * 32 + l31;                                      \
    const float bb_ = (col_ < DD) ? b1f[col_] : 0.f;                         \
    const int cc_ = col_ >> 3, c7_ = col_ & 7;                               \
    _Pragma("unroll")                                                        \
    for (int q_ = 0; q_ < 4; ++q_) {                                         \
        _Pragma("unroll")                                                    \
        for (int r_ = 0; r_ < 4; ++r_) {                                     \
            const int row_ = mrow0 + (MT) * 32 + q_ * 8 + 4 * lh + r_;       \
            XB[row_ * 320 + ((cc_ ^ (row_ & 7)) << 3) + c7_]                 \
                = (_Float16)(ACC[4 * q_ + r_] + bb_);                        \
        } }                                                                  \
} while (0)

// max over valid t for one tile, both mt accs. Only (wmg==1, mt==1,
// q==3, lh==1) rows (t=124..127) are invalid.
#define MAXT(A0, A1, TILE) do {                                              \
    float m_ = -3.0e38f;                                                     \
    _Pragma("unroll")                                                        \
    for (int q_ = 0; q_ < 4; ++q_) {                                         \
        _Pragma("unroll")                                                    \
        for (int r_ = 0; r_ < 4; ++r_) m_ = fmaxf(m_, A0[4 * q_ + r_]);      \
    }                                                                        \
    _Pragma("unroll")                                                        \
    for (int q_ = 0; q_ < 4; ++q_) {                                         \
        if (!(wmg == 1 && q_ == 3 && lh == 1)) {                             \
            _Pragma("unroll")                                                \
            for (int r_ = 0; r_ < 4; ++r_) m_ = fmaxf(m_, A1[4 * q_ + r_]);  \
        } }                                                                  \
    m_ = fmaxf(m_, __shfl_xor(m_, 32));                                      \
    if (lh == 0) pmax2[wmg][(TILE) * 32 + l31] = m_;                         \
} while (0)

__global__ __launch_bounds__(512, 2) void CNNEncoder_36258113912977_kernel(
    const int* __restrict__ tok, const void* mention, const void* emb,
    const void* W1, const void* b1, const void* conv_w, const void* conv_b,
    const void* W2, const void* b2, const void* W3, const void* b3,
    void* out, const void* ws)
{
    if (!sniff_is32(W1)) return;          // bf16 world -> scalar fallback

    // 84,480 + 2,560 + 2,400 + 1,200 = 90,640 B
    __shared__ __align__(16) _Float16 XB[132 * 320];   // X, then Xh
    __shared__ float pmax2[2][320];
    __shared__ float cbuf[2 * DD];
    __shared__ float hbuf[DD];

    const int n = blockIdx.x, tid = threadIdx.x;
    const int w   = tid >> 6;
    const int l   = tid & 63;
    const int l31 = l & 31, lh = l >> 5;
    const int wmg = w >> 2;                  // M group: rows [64*wmg, 64*wmg+64)
    const int wn  = w & 3;                   // N group: tiles {wn, wn+4, wn+8?}
    const bool nt3 = (wn < 2);
    const int mrow0 = wmg * 64;
    const int* trow = tok + (size_t)n * LL;
    const float* b1f = (const float*)b1;
    const f16x8* wsp = (const f16x8*)ws;

    // B granule indices (lane-fixed): plane-local [kc=lh][nn][16B]
    const int bg0 = lh * 320 + (wn    ) * 32 + l31;
    const int bg1 = lh * 320 + (wn + 4) * 32 + l31;
    const int bg2 = lh * 320 + (wn + 8) * 32 + l31;    // only if nt3

    f16x8 bE0, bE1, bE2, bO0, bO1, bO2;    // B parity regs
    f16x8 aE0, aE1, aO0, aO1;              // A parity regs

    // ---- issue B loads for phase 0 before any LDS work ----
    bE0 = wsp[bg0]; bE1 = wsp[bg1]; if (nt3) bE2 = wsp[bg2];

    // ---- zero-fill XB (pads rows 128..131, cols 300..319) ----
    for (int i = tid; i < 132 * 160; i += 512) ((u32*)XB)[i] = 0u;
    __syncthreads();

    // ---- gather 128 emb rows, fp32 -> fp16, 16B-chunk XOR swizzle ----
    {
        const int r = tid >> 2, q = tid & 3;
        const float* erow = (const float*)emb + (size_t)trow[r] * DD;
        for (int c = q; c < 38; c += 4) {
            f16x8 v;
            if (c < 37) {
                const float4 f0 = *(const float4*)(erow + 8 * c);
                const float4 f1 = *(const float4*)(erow + 8 * c + 4);
                v[0]=(_Float16)f0.x; v[1]=(_Float16)f0.y;
                v[2]=(_Float16)f0.z; v[3]=(_Float16)f0.w;
                v[4]=(_Float16)f1.x; v[5]=(_Float16)f1.y;
                v[6]=(_Float16)f1.z; v[7]=(_Float16)f1.w;
            } else {
                const float4 f0 = *(const float4*)(erow + 296);
                v[0]=(_Float16)f0.x; v[1]=(_Float16)f0.y;
                v[2]=(_Float16)f0.z; v[3]=(_Float16)f0.w;
                v[4]=(_Float16)0.f; v[5]=(_Float16)0.f;
                v[6]=(_Float16)0.f; v[7]=(_Float16)0.f;
            }
            const int p = c ^ (r & 7);
            *(f16x8*)&XB[r * 320 + (p << 3)] = v;
        }
    }
    __syncthreads();   // X visible to all waves

    // ---- A-frags for phase 0 ----
    {
        const int c_ = lh;
        { const int r_ = mrow0 + l31;
          aE0 = *(const f16x8*)&XB[r_ * 320 + ((c_ ^ (r_ & 7)) << 3)]; }
        { const int r_ = mrow0 + 32 + l31;
          aE1 = *(const f16x8*)&XB[r_ * 320 + ((c_ ^ (r_ & 7)) << 3)]; }
    }

    f32x16 acc00, acc01, acc02, acc10, acc11, acc12;
    #pragma unroll
    for (int j = 0; j < 16; ++j) {
        acc00[j] = 0.f; acc01[j] = 0.f; acc02[j] = 0.f;
        acc10[j] = 0.f; acc11[j] = 0.f; acc12[j] = 0.f;
    }

    // =========== GEMM1: phases 0..18, NO barriers ==========
    for (int p = 0; p < 18; p += 2) {
        G1(p,     bE0, bE1, bE2, aE0, aE1, bO0, bO1, bO2, aO0, aO1);
        G1(p + 1, bO0, bO1, bO2, aO0, aO1, bE0, bE1, bE2, aE0, aE1);
    }
    G1(18, bE0, bE1, bE2, aE0, aE1, bO0, bO1, bO2, aO0, aO1);
    // (conv plane 19's B now in O-parity regs)

    __syncthreads();   // all waves done READING X before Xh overwrites

    // epilogue: +b1, round to fp16, write Xh over XB (own rows/cols)
    EPI(acc00, 0, wn);      EPI(acc10, 1, wn);
    EPI(acc01, 0, wn + 4);  EPI(acc11, 1, wn + 4);
    if (nt3) { EPI(acc02, 0, wn + 8);  EPI(acc12, 1, wn + 8); }
    __syncthreads();   // Xh visible to all

    // ---- A-frags for conv phase 0 (s=0, kk=0) ----
    {
        const int c_ = lh;
        { const int r_ = mrow0 + l31;
          aO0 = *(const f16x8*)&XB[r_ * 320 + ((c_ ^ (r_ & 7)) << 3)]; }
        { const int r_ = mrow0 + 32 + l31;
          aO1 = *(const f16x8*)&XB[r_ * 320 + ((c_ ^ (r_ & 7)) << 3)]; }
    }

    #pragma unroll
    for (int j = 0; j < 16; ++j) {
        acc00[j] = 0.f; acc01[j] = 0.f; acc02[j] = 0.f;
        acc10[j] = 0.f; acc11[j] = 0.f; acc12[j] = 0.f;
    }

    // =========== conv: 95 phases, NO barriers ==========
    for (int c = 0; c < 94; c += 2) {
        CV(c,     bO0, bO1, bO2, aO0, aO1, bE0, bE1, bE2, aE0, aE1);
        CV(c + 1, bE0, bE1, bE2, aE0, aE1, bO0, bO1, bO2, aO0, aO1);
    }
    CV(94, bO0, bO1, bO2, aO0, aO1, bE0, bE1, bE2, aE0, aE1);

    // per-wave max over valid t, publish per-M-group
    MAXT(acc00, acc10, wn);
    MAXT(acc01, acc11, wn + 4);
    if (nt3) MAXT(acc02, acc12, wn + 8);
    __syncthreads();

    // ---- concat = [max + conv_b, mention[n]] ----
    if (tid < DD) {
        const float m = fmaxf(pmax2[0][tid], pmax2[1][tid]);
        cbuf[tid]      = m + ((const float*)conv_b)[tid];
        cbuf[DD + tid] = ((const float*)mention)[(size_t)n * DD + tid];
    }
    __syncthreads();

    // ---- h = tanh(concat @ W2 + b2) ----
    if (tid < DD) {
        const float* W2f = (const float*)W2;
        float a0 = 0.f, a1 = 0.f, a2 = 0.f, a3 = 0.f;
        for (int c = 0; c < 2 * DD; c += 4) {
            a0 += cbuf[c]     * W2f[(size_t)c * DD + tid];
            a1 += cbuf[c + 1] * W2f[(size_t)(c + 1) * DD + tid];
            a2 += cbuf[c + 2] * W2f[(size_t)(c + 2) * DD + tid];
            a3 += cbuf[c + 3] * W2f[(size_t)(c + 3) * DD + tid];
        }
        hbuf[tid] = tanhf(((const float*)b2)[tid] + (a0 + a1) + (a2 + a3));
    }
    __syncthreads();

    // ---- out = h @ W3 + b3 (fp32) ----
    if (tid < DD) {
        const float* W3f = (const float*)W3;
        float a0 = 0.f, a1 = 0.f;
        for (int c = 0; c < DD; c += 2) {
            a0 += hbuf[c]     * W3f[(size_t)c * DD + tid];
            a1 += hbuf[c + 1] * W3f[(size_t)(c + 1) * DD + tid];
        }
        ((float*)out)[(size_t)n * DD + tid] = ((const float*)b3)[tid] + a0 + a1;
    }
}

// ======== fallback: dual-world scalar kernel ========
// bf16 world always; fp32 world only when force32 (ws too small).
#define CH   16
#define XR   20
#define NSTG 8
__global__ void CNNEncoder_36258113912977_fallback(
    const int* tok, const void* mention, const void* emb,
    const void* W1, const void* b1, const void* conv_w, const void* conv_b,
    const void* W2, const void* b2, const void* W3, const void* b3,
    void* out, int force32)
{
    __shared__ float g[XR * DD];
    __shared__ float xh[XR * DD];
    __shared__ float concat[2 * DD];
    __shared__ float hbuf[DD];

    const int n = blockIdx.x, tid = threadIdx.x;
    const int* trow = tok + (size_t)n * LL;

    const int is32 = sniff_is32(W1);
    if (is32 && !force32) return;

    float mmax = -3.0e38f;

    for (int stage = 0; stage < NSTG; ++stage) {
        const int tbase = stage * CH;
        __syncthreads();

        for (int i = tid; i < XR * DD; i += BLK) {
            int r = i / DD, c = i - (i / DD) * DD;
            int gr = tbase + r; if (gr > 127) gr = 127;
            g[i] = ld(emb, (size_t)trow[gr] * DD + c, is32);
        }
        __syncthreads();

        if (tid < DD) {
            float acc[XR];
            #pragma unroll
            for (int r = 0; r < XR; ++r) acc[r] = 0.f;
            for (int k = 0; k < DD; ++k) {
                float wv = ld(W1, (size_t)k * DD + tid, is32);
                #pragma unroll
                for (int r = 0; r < XR; ++r) acc[r] += g[r * DD + k] * wv;
            }
            float bb = ld(b1, tid, is32);
            #pragma unroll
            for (int r = 0; r < XR; ++r) xh[r * DD + tid] = acc[r] + bb;
        }
        __syncthreads();

        if (tid < DD) {
            float y[CH];
            #pragma unroll
            for (int t = 0; t < CH; ++t) y[t] = 0.f;
            const size_t cwoff = (size_t)tid * (DD * 5);
            for (int k = 0; k < DD; ++k) {
                #pragma unroll
                for (int s = 0; s < 5; ++s) {
                    float wv = ld(conv_w, cwoff + k * 5 + s, is32);
                    #pragma unroll
                    for (int t = 0; t < CH; ++t)
                        y[t] += xh[(t + s) * DD + k] * wv;
                }
            }
            #pragma unroll
            for (int t = 0; t < CH; ++t) {
                int tt = tbase + t;
                if (tt < TOUT) mmax = fmaxf(mmax, y[t]);
            }
        }
    }

    __syncthreads();
    if (tid < DD) {
        concat[tid]      = mmax + ld(conv_b, tid, is32);
        concat[DD + tid] = ld(mention, (size_t)n * DD + tid, is32);
    }
    __syncthreads();

    if (tid < DD) {
        float a = ld(b2, tid, is32);
        for (int c = 0; c < 2 * DD; ++c)
            a += concat[c] * ld(W2, (size_t)c * DD + tid, is32);
        hbuf[tid] = tanhf(a);
    }
    __syncthreads();

    if (tid < DD) {
        float a = ld(b3, tid, is32);
        for (int c = 0; c < DD; ++c)
            a += hbuf[c] * ld(W3, (size_t)c * DD + tid, is32);
        size_t o = (size_t)n * DD + tid;
        if (is32) ((float*)out)[o] = a;
        else      ((u16*)out)[o] = f2bu(a);
    }
}

extern "C" void kernel_launch(void* const* d_in, const int* in_sizes, int n_in,
                              void* d_out, int out_size, void* d_ws, size_t ws_size,
                              hipStream_t stream)
{
    const int ws_ok = (d_ws != nullptr) && ws_size >= (size_t)WS_SMALL;

    if (ws_ok) {
        CNNEncoder_36258113912977_xform<<<dim3(19, 6), 512, 0, stream>>>(
            d_in[3], d_in[5], d_ws);
        CNNEncoder_36258113912977_kernel<<<1024, 512, 0, stream>>>(
            (const int*)d_in[0], d_in[1], d_in[2], d_in[3], d_in[4], d_in[5],
            d_in[6], d_in[7], d_in[8], d_in[9], d_in[10], d_out, d_ws);
    }

    CNNEncoder_36258113912977_fallback<<<1024, BLK, 0, stream>>>(
        (const int*)d_in[0], d_in[1], d_in[2], d_in[3], d_in[4], d_in[5],
        d_in[6], d_in[7], d_in[8], d_in[9], d_in[10], d_out,
        ws_ok ? 0 : 1);
}